// Round 7
// baseline (34.396 us; speedup 1.0000x reference)
//
#include <hip/hip_runtime.h>
#include <hip/hip_bf16.h>
#include <math.h>

// Problem constants: S=1000, C=100, L=50, B=20, K=64, N=16384
#define CC 100
#define LL 50
#define BB 20
#define KK 64

// ---------------------------------------------------------------------------
// Kernel 1: grid = CC blocks (one per course c), 256 threads (4 waves).
//   Q2[c,b] = (1 - sig(slide_[c]) - sig(guess_[c])) * sum_k Pm[k,c] * E[k,b]
//   G[c]   = sig(guess_[c])
// (unchanged from rounds 5-6)
// ---------------------------------------------------------------------------
__global__ __launch_bounds__(256) void compute_q_kernel(
    const float* __restrict__ P, const float* __restrict__ D,
    const float* __restrict__ P_A, const float* __restrict__ P_B,
    const float* __restrict__ P_C, const float* __restrict__ D_A,
    const float* __restrict__ D_B, const float* __restrict__ guess_,
    const float* __restrict__ slide_,
    float* __restrict__ Q2, float* __restrict__ G)
{
    const int c    = blockIdx.x;
    const int t    = threadIdx.x;
    const int w    = t >> 6;
    const int lane = t & 63;            // == k

    __shared__ float PCs[BB * BB];
    __shared__ float rowsum_sh[KK];

    if (t < (BB * BB) / 4) ((float4*)PCs)[t] = ((const float4*)P_C)[t];

    {
        const int k = t >> 2, q = t & 3;
        const float* __restrict__ pr  = P   + k * CC + q * 25;
        const float* __restrict__ par = P_A + k * CC + q * 25;
        const float* __restrict__ pbr = P_B + k * CC + q * 25;
        float s = 0.f;
        #pragma unroll
        for (int i = 0; i < 25; ++i) s += __expf(fmaf(pr[i], par[i], pbr[i]));
        s += __shfl_xor(s, 1);
        s += __shfl_xor(s, 2);
        if (q == 0) rowsum_sh[k] = s;
    }

    float dm[BB];
    {
        const float4* d4  = (const float4*)(D   + lane * BB);
        const float4* da4 = (const float4*)(D_A + lane * BB);
        const float4* db4 = (const float4*)(D_B + lane * BB);
        #pragma unroll
        for (int i = 0; i < 5; ++i) {
            const float4 dv = d4[i], av = da4[i], bv = db4[i];
            dm[4 * i + 0] = __expf(fmaf(dv.x, av.x, bv.x));
            dm[4 * i + 1] = __expf(fmaf(dv.y, av.y, bv.y));
            dm[4 * i + 2] = __expf(fmaf(dv.z, av.z, bv.z));
            dm[4 * i + 3] = __expf(fmaf(dv.w, av.w, bv.w));
        }
    }
    #pragma unroll
    for (int b = 0; b < BB; ++b) {
        float s = dm[b];
        s += __shfl_xor(s, 1);  s += __shfl_xor(s, 2);  s += __shfl_xor(s, 4);
        s += __shfl_xor(s, 8);  s += __shfl_xor(s, 16); s += __shfl_xor(s, 32);
        dm[b] *= (1.f / s);
    }
    __syncthreads();

    float ev[5];
    #pragma unroll
    for (int j = 0; j < 5; ++j) {
        const int b = 5 * w + j;
        float acc = 0.f;
        #pragma unroll
        for (int jj = 0; jj < BB; ++jj) acc = fmaf(dm[jj], PCs[jj * BB + b], acc);
        ev[j] = acc;
    }

    const float ps = fmaf(P[lane * CC + c], P_A[lane * CC + c], P_B[lane * CC + c]);
    const float pm = __expf(ps) / rowsum_sh[lane];

    float qv[5];
    #pragma unroll
    for (int j = 0; j < 5; ++j) {
        float v = pm * ev[j];
        v += __shfl_xor(v, 1);  v += __shfl_xor(v, 2);  v += __shfl_xor(v, 4);
        v += __shfl_xor(v, 8);  v += __shfl_xor(v, 16); v += __shfl_xor(v, 32);
        qv[j] = v;
    }
    if (lane == 0) {
        const float g  = 1.f / (1.f + __expf(-guess_[c]));
        const float sl = 1.f / (1.f + __expf(-slide_[c]));
        const float scale = 1.f - sl - g;
        #pragma unroll
        for (int j = 0; j < 5; ++j) Q2[c * BB + 5 * w + j] = qv[j] * scale;
        if (w == 0) G[c] = g;
    }
}

// ---------------------------------------------------------------------------
// Kernel 2: two samples per wave, no LDS, no barriers (round-6 structure).
// SINGLE CHANGE THIS ROUND: the csa gather uses NON-TEMPORAL loads (bypass
// L1/TCP allocation -> not limited by per-CU line-fill tracking; slices have
// zero intra-launch reuse so L1 caching was pure pollution), and the
// redundant g==3 mirror lanes are masked off (their duplicate loads would
// become real L2 traffic with L1 bypassed).
// ---------------------------------------------------------------------------
__global__ __launch_bounds__(256) void main_kernel(
    const float* __restrict__ X, const int* __restrict__ stu,
    const int* __restrict__ cour, const float* __restrict__ csa,
    const float* __restrict__ Q2, const float* __restrict__ G,
    float* __restrict__ out, int N)
{
    const int t = threadIdx.x;
    const int w = t >> 6, lane = t & 63;
    const int n0 = blockIdx.x * 8 + 2 * w;
    const int n1 = n0 + 1;
    if (n0 >= N) return;
    const bool hasB = (n1 < N);

    const int sA = stu[n0], cA = cour[n0];
    const int sB = hasB ? stu[n1] : sA;
    const int cB = hasB ? cour[n1] : cA;
    const float* __restrict__ baseA = csa + ((size_t)sA * CC + cA) * (size_t)(LL * BB);
    const float* __restrict__ baseB = csa + ((size_t)sB * CC + cB) * (size_t)(LL * BB);

    const int b = lane % BB;
    const int g = lane / BB;                      // 0..3; g==3 lanes are idle
    const bool act = (g < 3);
    const int l0 = act ? g * 17 : 0;
    const bool has17 = (g != 2);                  // g2 covers 16 rows

    // --- Cold gather, non-temporal, issued first. ---
    float va[16], vb[16];
    float va16 = 0.f, vb16 = 0.f;
    if (act) {
        #pragma unroll
        for (int i = 0; i < 16; ++i)
            va[i] = __builtin_nontemporal_load(baseA + (l0 + i) * BB + b);
        #pragma unroll
        for (int i = 0; i < 16; ++i)
            vb[i] = __builtin_nontemporal_load(baseB + (l0 + i) * BB + b);
        if (has17) {
            va16 = __builtin_nontemporal_load(baseA + (l0 + 16) * BB + b);
            vb16 = __builtin_nontemporal_load(baseB + (l0 + 16) * BB + b);
        }
    }

    // X rows: one coalesced load each, distributed by shuffle.
    const float xvA = (lane < LL) ? X[(size_t)n0 * LL + lane] : 0.f;
    const float xvB = (hasB && lane < LL) ? X[(size_t)n1 * LL + lane] : 0.f;

    // Hot operands (L1/L2): Q2 rows + G, shared by both samples.
    const int c1ok = (lane < CC - 64);
    float4 q0[5], q1[5];
    {
        const float4* Q2v0 = (const float4*)(Q2 + lane * BB);
        #pragma unroll
        for (int k = 0; k < 5; ++k) q0[k] = Q2v0[k];
        if (c1ok) {
            const float4* Q2v1 = (const float4*)(Q2 + (64 + lane) * BB);
            #pragma unroll
            for (int k = 0; k < 5; ++k) q1[k] = Q2v1[k];
        }
    }
    const float g0v = G[lane];
    const float g1v = c1ok ? G[64 + lane] : 0.f;

    // Fused column softmax + X-weighted reduce, both samples.
    float ssA = 0.f, tsA = 0.f, ssB = 0.f, tsB = 0.f;
    if (act) {
        #pragma unroll
        for (int i = 0; i < 16; ++i) {
            const float eA = __expf(va[i]);
            const float eB = __expf(vb[i]);
            ssA += eA; ssB += eB;
            tsA = fmaf(eA, __shfl(xvA, l0 + i), tsA);
            tsB = fmaf(eB, __shfl(xvB, l0 + i), tsB);
        }
        if (has17) {
            const float eA = __expf(va16);
            const float eB = __expf(vb16);
            ssA += eA; ssB += eB;
            tsA = fmaf(eA, __shfl(xvA, l0 + 16), tsA);
            tsB = fmaf(eB, __shfl(xvB, l0 + 16), tsB);
        }
    }

    // Combine 3 chunk partials per b for both samples.
    const float sTA = __shfl(ssA, b) + __shfl(ssA, b + BB) + __shfl(ssA, b + 2 * BB);
    const float tTA = __shfl(tsA, b) + __shfl(tsA, b + BB) + __shfl(tsA, b + 2 * BB);
    const float sTB = __shfl(ssB, b) + __shfl(ssB, b + BB) + __shfl(ssB, b + 2 * BB);
    const float tTB = __shfl(tsB, b) + __shfl(tsB, b + BB) + __shfl(tsB, b + 2 * BB);
    const float AvA = tTA / sTA;                  // lane j<20 holds A[n0][j]
    const float AvB = tTB / sTB;                  // lane j<20 holds A[n1][j]

    // Matvecs: out[n,c] = sum_b A[b]*Q2[c,b] + G[c], Q2 regs shared.
    float y0A = 0.f, y1A = 0.f, y0B = 0.f, y1B = 0.f;
    #pragma unroll
    for (int bb = 0; bb < BB; ++bb) {
        const float aA = __uint_as_float(
            __builtin_amdgcn_readlane(__float_as_uint(AvA), bb));
        const float aB = __uint_as_float(
            __builtin_amdgcn_readlane(__float_as_uint(AvB), bb));
        const float qv0 = ((const float*)q0)[bb];
        const float qv1 = ((const float*)q1)[bb];
        y0A = fmaf(aA, qv0, y0A);  y1A = fmaf(aA, qv1, y1A);
        y0B = fmaf(aB, qv0, y0B);  y1B = fmaf(aB, qv1, y1B);
    }
    float* orowA = out + (size_t)n0 * CC;
    orowA[lane] = y0A + g0v;
    if (c1ok) orowA[64 + lane] = y1A + g1v;
    if (hasB) {
        float* orowB = out + (size_t)n1 * CC;
        orowB[lane] = y0B + g0v;
        if (c1ok) orowB[64 + lane] = y1B + g1v;
    }
}

extern "C" void kernel_launch(void* const* d_in, const int* in_sizes, int n_in,
                              void* d_out, int out_size, void* d_ws, size_t ws_size,
                              hipStream_t stream) {
    const float* X      = (const float*)d_in[0];
    const int*   stu    = (const int*)  d_in[1];
    const int*   cour   = (const int*)  d_in[2];
    const float* csa    = (const float*)d_in[3];
    const float* P      = (const float*)d_in[4];
    const float* D      = (const float*)d_in[5];
    const float* P_A    = (const float*)d_in[6];
    const float* P_B    = (const float*)d_in[7];
    const float* P_C    = (const float*)d_in[8];
    const float* D_A    = (const float*)d_in[9];
    const float* D_B    = (const float*)d_in[10];
    const float* guess_ = (const float*)d_in[11];
    const float* slide_ = (const float*)d_in[12];
    float* out = (float*)d_out;
    float* Q2  = (float*)d_ws;            // C*B floats
    float* G   = (float*)d_ws + CC * BB;  // C floats

    const int N = in_sizes[1];   // 16384

    compute_q_kernel<<<CC, 256, 0, stream>>>(P, D, P_A, P_B, P_C, D_A, D_B,
                                             guess_, slide_, Q2, G);
    main_kernel<<<(N + 7) / 8, 256, 0, stream>>>(X, stu, cour, csa, Q2, G, out, N);
}